// Round 7
// baseline (571.977 us; speedup 1.0000x reference)
//
#include <hip/hip_runtime.h>
#include <math.h>
#include <type_traits>

#define N_NODES 50000
#define N_EDGES 800000
#define SCAN_BLK 2048   // elements per scan block (256 threads x 8)

using short8  = __attribute__((ext_vector_type(8))) short;
using floatx4 = __attribute__((ext_vector_type(4))) float;
using ushortx4 = __attribute__((ext_vector_type(4))) unsigned short;
using uintx2  = __attribute__((ext_vector_type(2))) unsigned;

__device__ inline unsigned short f2bf(float f) {
  unsigned u = __float_as_uint(f);
  u += 0x7fff + ((u >> 16) & 1);   // round-to-nearest-even
  return (unsigned short)(u >> 16);
}

__device__ inline float sigmoidf(float x) { return 1.0f / (1.0f + __expf(-x)); }

// ---------------- CSR build ----------------

__global__ void count_kernel(const int* __restrict__ rows, int* __restrict__ counts, int E) {
  int e = blockIdx.x * 256 + threadIdx.x;
  if (e < E) atomicAdd(&counts[rows[e]], 1);
}

// pass1: per-block sums. N % 8 == 0 so (base < N) => full 8 in-bounds.
__global__ void scan_pass1(const int* __restrict__ counts, int* __restrict__ bsum, int N) {
  int base = blockIdx.x * SCAN_BLK + threadIdx.x * 8;
  int s = 0;
  if (base < N) {
#pragma unroll
    for (int j = 0; j < 8; ++j) s += counts[base + j];
  }
#pragma unroll
  for (int d = 32; d > 0; d >>= 1) s += __shfl_down(s, d, 64);
  __shared__ int wsum[4];
  int lane = threadIdx.x & 63, wv = threadIdx.x >> 6;
  if (lane == 0) wsum[wv] = s;
  __syncthreads();
  if (threadIdx.x == 0) bsum[blockIdx.x] = wsum[0] + wsum[1] + wsum[2] + wsum[3];
}

// pass3 (pass2 folded in): wave0 computes this block's global offset from bsum
// (<=64 entries) in-wave; block 0 also writes row_ptr[N] = total.
__global__ void scan_pass3(const int* __restrict__ counts, const int* __restrict__ bsum,
                           int* __restrict__ row_ptr, int* __restrict__ cursor, int N, int B) {
  __shared__ int blk_off_s, total_s;
  int tid = threadIdx.x, lane = tid & 63, wv = tid >> 6;
  if (wv == 0) {
    int b = (lane < B) ? bsum[lane] : 0;
    int pre = (lane < (int)blockIdx.x) ? b : 0;   // sum of bsum[0..blockIdx-1]
    int tot = b;
#pragma unroll
    for (int d = 32; d > 0; d >>= 1) { pre += __shfl_down(pre, d, 64); tot += __shfl_down(tot, d, 64); }
    if (lane == 0) { blk_off_s = pre; total_s = tot; }
  }
  __syncthreads();
  if (blockIdx.x == 0 && tid == 0) row_ptr[N] = total_s;
  int base = blockIdx.x * SCAN_BLK + tid * 8;
  int v[8];
  int s = 0;
  if (base < N) {
#pragma unroll
    for (int j = 0; j < 8; ++j) { v[j] = counts[base + j]; s += v[j]; }
  } else {
#pragma unroll
    for (int j = 0; j < 8; ++j) v[j] = 0;
  }
  int x = s;
#pragma unroll
  for (int d = 1; d < 64; d <<= 1) {
    int y = __shfl_up(x, d, 64);
    if (lane >= d) x += y;
  }
  __shared__ int wsum[4];
  if (lane == 63) wsum[wv] = x;
  __syncthreads();
  int woff = 0;
  for (int w = 0; w < wv; ++w) woff += wsum[w];
  int run = blk_off_s + woff + (x - s);   // exclusive offset of this thread's first elem
  if (base < N) {
#pragma unroll
    for (int j = 0; j < 8; ++j) {
      row_ptr[base + j] = run;
      cursor[base + j] = run;
      run += v[j];
    }
  }
}

// packed {col, val_bits} 8B records: one store per edge, one load per edge-use.
__global__ void scatter_kernel(const int* __restrict__ rows, const int* __restrict__ cols,
                               const float* __restrict__ vals, int* __restrict__ cursor,
                               uintx2* __restrict__ colval, int E) {
  int e = blockIdx.x * 256 + threadIdx.x;
  if (e >= E) return;
  int r = rows[e];
  int p = atomicAdd(&cursor[r], 1);
  uintx2 cv;
  cv[0] = (unsigned)cols[e];
  cv[1] = __float_as_uint(vals[e]);
  colval[p] = cv;
}

// ---------------- fused cast (x -> bf16) + weight pack ----------------
// Blocks [0, castB): cast x (n4 float4 groups). Blocks [castB, castB+768): pack weights.
// W [K,M] row-major -> Wp[m*K+k] = bf16(W[k,m]).
__global__ void cast_pack_kernel(const float* __restrict__ x, unsigned short* __restrict__ xb, int n4,
                                 int castB,
                                 const float* __restrict__ W1, const float* __restrict__ G1,
                                 const float* __restrict__ W2, const float* __restrict__ G2,
                                 unsigned short* __restrict__ Wp1, unsigned short* __restrict__ Gp1,
                                 unsigned short* __restrict__ Wp2, unsigned short* __restrict__ Gp2) {
  if ((int)blockIdx.x < castB) {
    int i = blockIdx.x * 256 + threadIdx.x;
    if (i >= n4) return;
    floatx4 v = ((const floatx4*)x)[i];
    ushortx4 o;
    o[0] = f2bf(v[0]); o[1] = f2bf(v[1]); o[2] = f2bf(v[2]); o[3] = f2bf(v[3]);
    ((ushortx4*)xb)[i] = o;
  } else {
    int idx = (blockIdx.x - castB) * 256 + threadIdx.x;
    if (idx < 65536) {
      int m = idx >> 8, k = idx & 255;
      Wp1[idx] = f2bf(W1[k * 256 + m]);
    } else if (idx < 131072) {
      int t = idx - 65536; int m = t >> 8, k = t & 255;
      Gp1[t] = f2bf(G1[k * 256 + m]);
    } else if (idx < 163840) {
      int t = idx - 131072; int m = t >> 8, k = t & 255;
      Wp2[t] = f2bf(W2[k * 128 + m]);
    } else {
      int t = idx - 163840; int m = t >> 8, k = t & 255;
      Gp2[t] = f2bf(G2[k * 128 + m]);
    }
  }
}

// ---------------- fused dual GEMM: S = A@W, G = A@G, written interleaved bf16 ----------------
// Block = 64 rows x M cols; wave wid owns col-tiles [wid*WT, (wid+1)*WT) across ALL 64 rows.
// A frag: lane holds A[m=lane&15][k=quad*8+j]; C/D: D[row=quad*4+reg][col=lane&15] (m89/m91)
template <int MT_TOTAL>   // M = MT_TOTAL*16; WT = MT_TOTAL/4 col tiles per wave
__global__ __launch_bounds__(256) void gemm_dual_kernel(const unsigned short* __restrict__ A,
                                                        const unsigned short* __restrict__ Wp,
                                                        const unsigned short* __restrict__ Gp,
                                                        unsigned* __restrict__ SG, int N) {
  constexpr int K = 256;
  constexpr int M = MT_TOTAL * 16;
  constexpr int WT = MT_TOTAL / 4;
  int lane = threadIdx.x & 63;
  int wid = threadIdx.x >> 6;
  int r0 = blockIdx.x * 64;
  if (r0 >= N) return;
  int quad = lane >> 4, lr = lane & 15;
  int t0 = wid * WT;

  const short* Ab[4];
#pragma unroll
  for (int g = 0; g < 4; ++g) {
    int row = r0 + g * 16 + lr;
    if (row > N - 1) row = N - 1;   // clamp loads; stores guarded below
    Ab[g] = (const short*)A + (size_t)row * K + quad * 8;
  }
  const short* Wb[WT];
  const short* Gb[WT];
#pragma unroll
  for (int t = 0; t < WT; ++t) {
    size_t boff = (size_t)(t0 + t) * 16 * K + (size_t)lr * K + quad * 8;
    Wb[t] = (const short*)Wp + boff;
    Gb[t] = (const short*)Gp + boff;
  }

  floatx4 zero = {0.f, 0.f, 0.f, 0.f};
  floatx4 accS[4][WT], accG[4][WT];
#pragma unroll
  for (int g = 0; g < 4; ++g)
#pragma unroll
    for (int t = 0; t < WT; ++t) { accS[g][t] = zero; accG[g][t] = zero; }

  for (int kc = 0; kc < K / 32; ++kc) {
    short8 a[4];
#pragma unroll
    for (int g = 0; g < 4; ++g) a[g] = *(const short8*)(Ab[g] + kc * 32);
#pragma unroll
    for (int t = 0; t < WT; ++t) {
      short8 bw = *(const short8*)(Wb[t] + kc * 32);
      short8 bg = *(const short8*)(Gb[t] + kc * 32);
#pragma unroll
      for (int g = 0; g < 4; ++g) {
        accS[g][t] = __builtin_amdgcn_mfma_f32_16x16x32_bf16(a[g], bw, accS[g][t], 0, 0, 0);
        accG[g][t] = __builtin_amdgcn_mfma_f32_16x16x32_bf16(a[g], bg, accG[g][t], 0, 0, 0);
      }
    }
  }

#pragma unroll
  for (int g = 0; g < 4; ++g) {
    int orow = r0 + g * 16 + quad * 4;
#pragma unroll
    for (int t = 0; t < WT; ++t)
#pragma unroll
      for (int gg = 0; gg < 4; ++gg) {
        int row = orow + gg;
        if (row < N) {
          unsigned s = f2bf(accS[g][t][gg]);
          unsigned g2 = f2bf(accG[g][t][gg]);
          SG[(size_t)row * M + (t0 + t) * 16 + lr] = s | (g2 << 16);
        }
      }
  }
}

// ---------------- XCD-chunked fused SpMM pair + gating ----------------
// Feature dim split into 8 chunks (FPC = D/8 feats, FPC*4 bytes/row-chunk); chunk
// bound to blockIdx&7 = XCD (round-robin heuristic) so each XCD's L2 only caches
// its 1/8 slice of SG (6.4 MB for D=256, 3.2 MB for D=128) -> L2-miss rate drops.
// Lane split: lane/(FPC) picks one of EPL=64/FPC edges per load; lane%FPC = feature.
// Cross-edge partials combined via shfl_xor at the end. Gate read as asfloat(u):
// low-16 S bits perturb G mantissa <2^-8 rel.
template <int D, bool WRITE_H>
__global__ __launch_bounds__(256) void spmm_gated_kernel(const int* __restrict__ row_ptr,
                                                         const uintx2* __restrict__ colval,
                                                         const unsigned* __restrict__ SG,
                                                         unsigned short* __restrict__ hb,
                                                         float* __restrict__ out, int N) {
  constexpr int FPC = D / 8;        // 32 (D=256) or 16 (D=128)
  constexpr int EPL = 64 / FPC;     // 2 or 4 edges per load instruction
  int lane = threadIdx.x & 63;
  int wid = threadIdx.x >> 6;
  int chunk = blockIdx.x & 7;
  int r = (blockIdx.x >> 3) * 4 + wid;
  if (r >= N) return;
  int le = lane / FPC;              // which edge in the group
  int feat = lane & (FPC - 1);
  int fb = chunk * FPC + feat;      // uint offset within row

  int e0 = row_ptr[r], e1 = row_ptr[r + 1];
  float aS = 0.f, aG = 0.f;

  for (int e = e0; e < e1; e += 4 * EPL) {
    unsigned c[4];
    float v[4];
#pragma unroll
    for (int i = 0; i < 4; ++i) {
      int ei = e + EPL * i + le;
      int eic = (ei < e1) ? ei : e1 - 1;
      uintx2 cv = colval[eic];
      c[i] = cv[0];
      v[i] = (ei < e1) ? __uint_as_float(cv[1]) : 0.f;
    }
    unsigned p[4];
#pragma unroll
    for (int i = 0; i < 4; ++i) p[i] = SG[(size_t)c[i] * D + fb];
#pragma unroll
    for (int i = 0; i < 4; ++i) {
      aS += __uint_as_float(p[i] << 16) * v[i];
      aG += __uint_as_float(p[i]) * v[i];   // G + <2^-8 rel mantissa noise
    }
  }

  // combine edge-group partials
  aS += __shfl_xor(aS, 32, 64);
  aG += __shfl_xor(aG, 32, 64);
  if constexpr (EPL == 4) {
    aS += __shfl_xor(aS, 16, 64);
    aG += __shfl_xor(aG, 16, 64);
  }

  if (lane < FPC) {
    float h = sigmoidf(aG) * aS;
    if constexpr (WRITE_H) {
      h = h > 0.f ? h : 0.f;
      hb[(size_t)r * 256 + fb] = f2bf(h);
    } else {
      out[(size_t)r * D + fb] = h;
    }
  }
}

// ---------------- launch ----------------

extern "C" void kernel_launch(void* const* d_in, const int* in_sizes, int n_in,
                              void* d_out, int out_size, void* d_ws, size_t ws_size,
                              hipStream_t stream) {
  const float* x    = (const float*)d_in[0];
  const int*   rows = (const int*)d_in[1];
  const int*   cols = (const int*)d_in[2];
  const float* vals = (const float*)d_in[3];
  const float* W1   = (const float*)d_in[4];
  const float* G1   = (const float*)d_in[5];
  const float* W2   = (const float*)d_in[6];
  const float* G2   = (const float*)d_in[7];

  const int N = N_NODES, E = N_EDGES;
  char* ws = (char*)d_ws;
  size_t off = 0;
  auto alloc = [&](size_t bytes) -> char* {
    off = (off + 255) & ~(size_t)255;
    char* p = ws + off;
    off += bytes;
    return p;
  };
  int*   counts  = (int*)alloc((size_t)N * 4);
  int*   row_ptr = (int*)alloc((size_t)(N + 1) * 4);
  int*   cursor  = (int*)alloc((size_t)N * 4);
  int*   bsum    = (int*)alloc(64 * 4);
  uintx2* colval = (uintx2*)alloc((size_t)E * 8);
  unsigned short* xb  = (unsigned short*)alloc((size_t)N * 256 * 2);
  unsigned short* hb  = (unsigned short*)alloc((size_t)N * 256 * 2);
  unsigned short* Wp1 = (unsigned short*)alloc(256 * 256 * 2);
  unsigned short* Gp1 = (unsigned short*)alloc(256 * 256 * 2);
  unsigned short* Wp2 = (unsigned short*)alloc(256 * 128 * 2);
  unsigned short* Gp2 = (unsigned short*)alloc(256 * 128 * 2);
  unsigned* SG1 = (unsigned*)alloc((size_t)N * 256 * 4);   // [N][256] uints = {S,G} bf16 pairs
  unsigned* SG2 = (unsigned*)alloc((size_t)N * 128 * 4);   // [N][128] uints

  // CSR build (per launch; same work every call)
  (void)hipMemsetAsync(counts, 0, (size_t)N * 4, stream);
  count_kernel<<<(E + 255) / 256, 256, 0, stream>>>(rows, counts, E);
  int scanB = (N + SCAN_BLK - 1) / SCAN_BLK;   // 25
  scan_pass1<<<scanB, 256, 0, stream>>>(counts, bsum, N);
  scan_pass3<<<scanB, 256, 0, stream>>>(counts, bsum, row_ptr, cursor, N, scanB);
  scatter_kernel<<<(E + 255) / 256, 256, 0, stream>>>(rows, cols, vals, cursor, colval, E);

  // fused cast + pack
  int n4 = N * 256 / 4;
  int castB = (n4 + 255) / 256;
  cast_pack_kernel<<<castB + 768, 256, 0, stream>>>(x, xb, n4, castB,
                                                    W1, G1, W2, G2, Wp1, Gp1, Wp2, Gp2);

  int gemm_blocks = (N + 63) / 64;
  int spmm_blocks = (N / 4) * 8;   // (row-quad) x 8 chunks; chunk = blockIdx & 7

  // layer 1
  gemm_dual_kernel<16><<<gemm_blocks, 256, 0, stream>>>(xb, Wp1, Gp1, SG1, N);
  spmm_gated_kernel<256, true><<<spmm_blocks, 256, 0, stream>>>(row_ptr, colval, SG1, hb, nullptr, N);
  // layer 2
  gemm_dual_kernel<8><<<gemm_blocks, 256, 0, stream>>>(hb, Wp2, Gp2, SG2, N);
  spmm_gated_kernel<128, false><<<spmm_blocks, 256, 0, stream>>>(row_ptr, colval, SG2, nullptr, (float*)d_out, N);
}

// Round 8
// 447.286 us; speedup vs baseline: 1.2788x; 1.2788x over previous
//
#include <hip/hip_runtime.h>
#include <math.h>
#include <type_traits>

#define N_NODES 50000
#define N_EDGES 800000
#define SCAN_BLK 2048   // elements per scan block (256 threads x 8)

using short8  = __attribute__((ext_vector_type(8))) short;
using floatx4 = __attribute__((ext_vector_type(4))) float;
using floatx2 = __attribute__((ext_vector_type(2))) float;
using ushortx4 = __attribute__((ext_vector_type(4))) unsigned short;
using uintx4  = __attribute__((ext_vector_type(4))) unsigned;
using uintx2  = __attribute__((ext_vector_type(2))) unsigned;

__device__ inline unsigned short f2bf(float f) {
  unsigned u = __float_as_uint(f);
  u += 0x7fff + ((u >> 16) & 1);   // round-to-nearest-even
  return (unsigned short)(u >> 16);
}

__device__ inline float sigmoidf(float x) { return 1.0f / (1.0f + __expf(-x)); }

// ---------------- fused prep: edge count + x cast + weight pack ----------------
// Blocks [0, cntB): count rows. [cntB, cntB+castB): cast x to bf16.
// [cntB+castB, +768): pack weights W [K,M] -> Wp[m*K+k] = bf16(W[k,m]).
__global__ void prep_kernel(const int* __restrict__ rows, int* __restrict__ counts, int E, int cntB,
                            const float* __restrict__ x, unsigned short* __restrict__ xb, int n4, int castB,
                            const float* __restrict__ W1, const float* __restrict__ G1,
                            const float* __restrict__ W2, const float* __restrict__ G2,
                            unsigned short* __restrict__ Wp1, unsigned short* __restrict__ Gp1,
                            unsigned short* __restrict__ Wp2, unsigned short* __restrict__ Gp2) {
  int b = blockIdx.x;
  if (b < cntB) {
    int e = b * 256 + threadIdx.x;
    if (e < E) atomicAdd(&counts[rows[e]], 1);
  } else if (b < cntB + castB) {
    int i = (b - cntB) * 256 + threadIdx.x;
    if (i >= n4) return;
    floatx4 v = ((const floatx4*)x)[i];
    ushortx4 o;
    o[0] = f2bf(v[0]); o[1] = f2bf(v[1]); o[2] = f2bf(v[2]); o[3] = f2bf(v[3]);
    ((ushortx4*)xb)[i] = o;
  } else {
    int idx = (b - cntB - castB) * 256 + threadIdx.x;
    if (idx < 65536) {
      int m = idx >> 8, k = idx & 255;
      Wp1[idx] = f2bf(W1[k * 256 + m]);
    } else if (idx < 131072) {
      int t = idx - 65536; int m = t >> 8, k = t & 255;
      Gp1[t] = f2bf(G1[k * 256 + m]);
    } else if (idx < 163840) {
      int t = idx - 131072; int m = t >> 8, k = t & 255;
      Wp2[t] = f2bf(W2[k * 128 + m]);
    } else {
      int t = idx - 163840; int m = t >> 8, k = t & 255;
      Gp2[t] = f2bf(G2[k * 128 + m]);
    }
  }
}

// ---------------- single-kernel exclusive scan ----------------
// Each block independently sums counts[0 .. blockIdx*SCAN_BLK) (int4 strided; <=196KB,
// L2-resident) for its global offset, then does the local 8-per-thread scan.
__global__ void scan_kernel(const int* __restrict__ counts, int* __restrict__ row_ptr,
                            int* __restrict__ cursor, int N, int E) {
  int tid = threadIdx.x, lane = tid & 63, wv = tid >> 6;
  __shared__ int wpart[4], wsum[4];

  // block offset
  int limit4 = (blockIdx.x * SCAN_BLK) >> 2;
  const int4* c4 = (const int4*)counts;
  int s = 0;
  for (int i = tid; i < limit4; i += 256) {
    int4 v = c4[i];
    s += v.x + v.y + v.z + v.w;
  }
#pragma unroll
  for (int d = 32; d > 0; d >>= 1) s += __shfl_down(s, d, 64);
  if (lane == 0) wpart[wv] = s;
  __syncthreads();
  int blk_off = wpart[0] + wpart[1] + wpart[2] + wpart[3];

  if (blockIdx.x == 0 && tid == 0) row_ptr[N] = E;   // grand total is E by construction

  // local scan
  int base = blockIdx.x * SCAN_BLK + tid * 8;
  int v[8];
  int sl = 0;
  if (base < N) {
#pragma unroll
    for (int j = 0; j < 8; ++j) { v[j] = counts[base + j]; sl += v[j]; }
  } else {
#pragma unroll
    for (int j = 0; j < 8; ++j) v[j] = 0;
  }
  int x = sl;
#pragma unroll
  for (int d = 1; d < 64; d <<= 1) {
    int y = __shfl_up(x, d, 64);
    if (lane >= d) x += y;
  }
  if (lane == 63) wsum[wv] = x;
  __syncthreads();
  int woff = 0;
  for (int w = 0; w < wv; ++w) woff += wsum[w];
  int run = blk_off + woff + (x - sl);   // exclusive offset of this thread's first elem
  if (base < N) {
#pragma unroll
    for (int j = 0; j < 8; ++j) {
      row_ptr[base + j] = run;
      cursor[base + j] = run;
      run += v[j];
    }
  }
}

// packed {col, val_bits} 8B records: one store per edge, one load per edge-use.
__global__ void scatter_kernel(const int* __restrict__ rows, const int* __restrict__ cols,
                               const float* __restrict__ vals, int* __restrict__ cursor,
                               uintx2* __restrict__ colval, int E) {
  int e = blockIdx.x * 256 + threadIdx.x;
  if (e >= E) return;
  int r = rows[e];
  int p = atomicAdd(&cursor[r], 1);
  uintx2 cv;
  cv[0] = (unsigned)cols[e];
  cv[1] = __float_as_uint(vals[e]);
  colval[p] = cv;
}

// ---------------- fused dual GEMM: S = A@W, G = A@G, written interleaved bf16 ----------------
// Block = 64 rows x M cols; wave wid owns col-tiles [wid*WT, (wid+1)*WT) across ALL 64 rows.
// A frag: lane holds A[m=lane&15][k=quad*8+j]; C/D: D[row=quad*4+reg][col=lane&15] (m89/m91)
template <int MT_TOTAL>   // M = MT_TOTAL*16; WT = MT_TOTAL/4 col tiles per wave
__global__ __launch_bounds__(256) void gemm_dual_kernel(const unsigned short* __restrict__ A,
                                                        const unsigned short* __restrict__ Wp,
                                                        const unsigned short* __restrict__ Gp,
                                                        unsigned* __restrict__ SG, int N) {
  constexpr int K = 256;
  constexpr int M = MT_TOTAL * 16;
  constexpr int WT = MT_TOTAL / 4;
  int lane = threadIdx.x & 63;
  int wid = threadIdx.x >> 6;
  int r0 = blockIdx.x * 64;
  if (r0 >= N) return;
  int quad = lane >> 4, lr = lane & 15;
  int t0 = wid * WT;

  const short* Ab[4];
#pragma unroll
  for (int g = 0; g < 4; ++g) {
    int row = r0 + g * 16 + lr;
    if (row > N - 1) row = N - 1;   // clamp loads; stores guarded below
    Ab[g] = (const short*)A + (size_t)row * K + quad * 8;
  }
  const short* Wb[WT];
  const short* Gb[WT];
#pragma unroll
  for (int t = 0; t < WT; ++t) {
    size_t boff = (size_t)(t0 + t) * 16 * K + (size_t)lr * K + quad * 8;
    Wb[t] = (const short*)Wp + boff;
    Gb[t] = (const short*)Gp + boff;
  }

  floatx4 zero = {0.f, 0.f, 0.f, 0.f};
  floatx4 accS[4][WT], accG[4][WT];
#pragma unroll
  for (int g = 0; g < 4; ++g)
#pragma unroll
    for (int t = 0; t < WT; ++t) { accS[g][t] = zero; accG[g][t] = zero; }

  for (int kc = 0; kc < K / 32; ++kc) {
    short8 a[4];
#pragma unroll
    for (int g = 0; g < 4; ++g) a[g] = *(const short8*)(Ab[g] + kc * 32);
#pragma unroll
    for (int t = 0; t < WT; ++t) {
      short8 bw = *(const short8*)(Wb[t] + kc * 32);
      short8 bg = *(const short8*)(Gb[t] + kc * 32);
#pragma unroll
      for (int g = 0; g < 4; ++g) {
        accS[g][t] = __builtin_amdgcn_mfma_f32_16x16x32_bf16(a[g], bw, accS[g][t], 0, 0, 0);
        accG[g][t] = __builtin_amdgcn_mfma_f32_16x16x32_bf16(a[g], bg, accG[g][t], 0, 0, 0);
      }
    }
  }

#pragma unroll
  for (int g = 0; g < 4; ++g) {
    int orow = r0 + g * 16 + quad * 4;
#pragma unroll
    for (int t = 0; t < WT; ++t)
#pragma unroll
      for (int gg = 0; gg < 4; ++gg) {
        int row = orow + gg;
        if (row < N) {
          unsigned s = f2bf(accS[g][t][gg]);
          unsigned g2 = f2bf(accG[g][t][gg]);
          SG[(size_t)row * M + (t0 + t) * 16 + lr] = s | (g2 << 16);
        }
      }
  }
}

// ---------------- fused SpMM pair + gating (bf16 interleaved SG input) ----------------
// R4 structure (best measured: 112us, 33% VALU): one wave per row, 4-deep full-row
// 16B/lane gathers + scalar remainder. Metadata as packed 8B {col,val} records.
// Gate read as asfloat(u): low-16 S bits perturb G mantissa <2^-8 rel.
template <int D, bool WRITE_H>
__global__ __launch_bounds__(256) void spmm_gated_kernel(const int* __restrict__ row_ptr,
                                                         const uintx2* __restrict__ colval,
                                                         const unsigned* __restrict__ SG,
                                                         unsigned short* __restrict__ hb,
                                                         float* __restrict__ out, int N) {
  constexpr int PF = D / 64;   // uints (SG pairs) per lane: 4 for D=256, 2 for D=128
  using uvec = typename std::conditional<PF == 4, uintx4, uintx2>::type;
  int lane = threadIdx.x & 63;
  int wid = threadIdx.x >> 6;
  int r = blockIdx.x * 4 + wid;
  if (r >= N) return;
  int e0 = row_ptr[r], e1 = row_ptr[r + 1];

  float aS[PF], aG[PF];
#pragma unroll
  for (int i = 0; i < PF; ++i) { aS[i] = 0.f; aG[i] = 0.f; }

  int e = e0;
  for (; e + 4 <= e1; e += 4) {
    uintx2 cv0 = colval[e], cv1 = colval[e + 1], cv2 = colval[e + 2], cv3 = colval[e + 3];
    uvec p0 = ((const uvec*)(SG + (size_t)cv0[0] * D))[lane];
    uvec p1 = ((const uvec*)(SG + (size_t)cv1[0] * D))[lane];
    uvec p2 = ((const uvec*)(SG + (size_t)cv2[0] * D))[lane];
    uvec p3 = ((const uvec*)(SG + (size_t)cv3[0] * D))[lane];
    float v0 = __uint_as_float(cv0[1]), v1 = __uint_as_float(cv1[1]);
    float v2 = __uint_as_float(cv2[1]), v3 = __uint_as_float(cv3[1]);
#pragma unroll
    for (int q = 0; q < PF; ++q) { aS[q] += __uint_as_float(p0[q] << 16) * v0; aG[q] += __uint_as_float(p0[q]) * v0; }
#pragma unroll
    for (int q = 0; q < PF; ++q) { aS[q] += __uint_as_float(p1[q] << 16) * v1; aG[q] += __uint_as_float(p1[q]) * v1; }
#pragma unroll
    for (int q = 0; q < PF; ++q) { aS[q] += __uint_as_float(p2[q] << 16) * v2; aG[q] += __uint_as_float(p2[q]) * v2; }
#pragma unroll
    for (int q = 0; q < PF; ++q) { aS[q] += __uint_as_float(p3[q] << 16) * v3; aG[q] += __uint_as_float(p3[q]) * v3; }
  }
  for (; e < e1; ++e) {
    uintx2 cv = colval[e];
    uvec p = ((const uvec*)(SG + (size_t)cv[0] * D))[lane];
    float v = __uint_as_float(cv[1]);
#pragma unroll
    for (int q = 0; q < PF; ++q) { aS[q] += __uint_as_float(p[q] << 16) * v; aG[q] += __uint_as_float(p[q]) * v; }
  }

  if constexpr (WRITE_H) {
    ushortx4 o;
#pragma unroll
    for (int i = 0; i < PF; ++i) {
      float h = sigmoidf(aG[i]) * aS[i];
      o[i] = f2bf(h > 0.f ? h : 0.f);
    }
    ((ushortx4*)(hb + (size_t)r * 256))[lane] = o;   // only instantiated with D=256
  } else {
    if constexpr (PF == 4) {
      floatx4 o;
#pragma unroll
      for (int i = 0; i < 4; ++i) o[i] = sigmoidf(aG[i]) * aS[i];
      ((floatx4*)(out + (size_t)r * D))[lane] = o;
    } else {
      floatx2 o;
#pragma unroll
      for (int i = 0; i < 2; ++i) o[i] = sigmoidf(aG[i]) * aS[i];
      ((floatx2*)(out + (size_t)r * D))[lane] = o;
    }
  }
}

// ---------------- launch ----------------

extern "C" void kernel_launch(void* const* d_in, const int* in_sizes, int n_in,
                              void* d_out, int out_size, void* d_ws, size_t ws_size,
                              hipStream_t stream) {
  const float* x    = (const float*)d_in[0];
  const int*   rows = (const int*)d_in[1];
  const int*   cols = (const int*)d_in[2];
  const float* vals = (const float*)d_in[3];
  const float* W1   = (const float*)d_in[4];
  const float* G1   = (const float*)d_in[5];
  const float* W2   = (const float*)d_in[6];
  const float* G2   = (const float*)d_in[7];

  const int N = N_NODES, E = N_EDGES;
  char* ws = (char*)d_ws;
  size_t off = 0;
  auto alloc = [&](size_t bytes) -> char* {
    off = (off + 255) & ~(size_t)255;
    char* p = ws + off;
    off += bytes;
    return p;
  };
  int*   counts  = (int*)alloc((size_t)N * 4);
  int*   row_ptr = (int*)alloc((size_t)(N + 1) * 4);
  int*   cursor  = (int*)alloc((size_t)N * 4);
  uintx2* colval = (uintx2*)alloc((size_t)E * 8);
  unsigned short* xb  = (unsigned short*)alloc((size_t)N * 256 * 2);
  unsigned short* hb  = (unsigned short*)alloc((size_t)N * 256 * 2);
  unsigned short* Wp1 = (unsigned short*)alloc(256 * 256 * 2);
  unsigned short* Gp1 = (unsigned short*)alloc(256 * 256 * 2);
  unsigned short* Wp2 = (unsigned short*)alloc(256 * 128 * 2);
  unsigned short* Gp2 = (unsigned short*)alloc(256 * 128 * 2);
  unsigned* SG1 = (unsigned*)alloc((size_t)N * 256 * 4);   // [N][256] uints = {S,G} bf16 pairs
  unsigned* SG2 = (unsigned*)alloc((size_t)N * 128 * 4);   // [N][128] uints

  (void)hipMemsetAsync(counts, 0, (size_t)N * 4, stream);

  // fused prep: count + cast + pack
  int cntB = (E + 255) / 256;           // 3125
  int n4 = N * 256 / 4;
  int castB = (n4 + 255) / 256;         // 12500
  prep_kernel<<<cntB + castB + 768, 256, 0, stream>>>(rows, counts, E, cntB,
                                                      x, xb, n4, castB,
                                                      W1, G1, W2, G2, Wp1, Gp1, Wp2, Gp2);

  // single-kernel scan + scatter
  int scanB = (N + SCAN_BLK - 1) / SCAN_BLK;   // 25
  scan_kernel<<<scanB, 256, 0, stream>>>(counts, row_ptr, cursor, N, E);
  scatter_kernel<<<cntB, 256, 0, stream>>>(rows, cols, vals, cursor, colval, E);

  int gemm_blocks = (N + 63) / 64;
  int spmm_blocks = (N + 3) / 4;

  // layer 1
  gemm_dual_kernel<16><<<gemm_blocks, 256, 0, stream>>>(xb, Wp1, Gp1, SG1, N);
  spmm_gated_kernel<256, true><<<spmm_blocks, 256, 0, stream>>>(row_ptr, colval, SG1, hb, nullptr, N);
  // layer 2
  gemm_dual_kernel<8><<<gemm_blocks, 256, 0, stream>>>(hb, Wp2, Gp2, SG2, N);
  spmm_gated_kernel<128, false><<<spmm_blocks, 256, 0, stream>>>(row_ptr, colval, SG2, nullptr, (float*)d_out, N);
}

// Round 9
// 436.264 us; speedup vs baseline: 1.3111x; 1.0253x over previous
//
#include <hip/hip_runtime.h>
#include <math.h>
#include <type_traits>

#define N_NODES 50000
#define N_EDGES 800000
#define SCAN_BLK 2048   // elements per scan block (256 threads x 8)
#define LDS_STRIDE 264  // 256 shorts + 8 pad (bank spread)

using short8  = __attribute__((ext_vector_type(8))) short;
using floatx4 = __attribute__((ext_vector_type(4))) float;
using floatx2 = __attribute__((ext_vector_type(2))) float;
using ushortx4 = __attribute__((ext_vector_type(4))) unsigned short;
using uintx4  = __attribute__((ext_vector_type(4))) unsigned;
using uintx2  = __attribute__((ext_vector_type(2))) unsigned;

__device__ inline unsigned short f2bf(float f) {
  unsigned u = __float_as_uint(f);
  u += 0x7fff + ((u >> 16) & 1);   // round-to-nearest-even
  return (unsigned short)(u >> 16);
}

__device__ inline float sigmoidf(float x) { return 1.0f / (1.0f + __expf(-x)); }

// ---------------- prep: edge count + weight pack ----------------
__global__ void prep_kernel(const int* __restrict__ rows, int* __restrict__ counts, int E, int cntB,
                            const float* __restrict__ W1, const float* __restrict__ G1,
                            const float* __restrict__ W2, const float* __restrict__ G2,
                            unsigned short* __restrict__ Wp1, unsigned short* __restrict__ Gp1,
                            unsigned short* __restrict__ Wp2, unsigned short* __restrict__ Gp2) {
  int b = blockIdx.x;
  if (b < cntB) {
    int e = b * 256 + threadIdx.x;
    if (e < E) atomicAdd(&counts[rows[e]], 1);
  } else {
    int idx = (b - cntB) * 256 + threadIdx.x;
    if (idx < 65536) {
      int m = idx >> 8, k = idx & 255;
      Wp1[idx] = f2bf(W1[k * 256 + m]);
    } else if (idx < 131072) {
      int t = idx - 65536; int m = t >> 8, k = t & 255;
      Gp1[t] = f2bf(G1[k * 256 + m]);
    } else if (idx < 163840) {
      int t = idx - 131072; int m = t >> 8, k = t & 255;
      Wp2[t] = f2bf(W2[k * 128 + m]);
    } else {
      int t = idx - 163840; int m = t >> 8, k = t & 255;
      Gp2[t] = f2bf(G2[k * 128 + m]);
    }
  }
}

// ---------------- single-kernel exclusive scan ----------------
__global__ void scan_kernel(const int* __restrict__ counts, int* __restrict__ row_ptr,
                            int* __restrict__ cursor, int N, int E) {
  int tid = threadIdx.x, lane = tid & 63, wv = tid >> 6;
  __shared__ int wpart[4], wsum[4];

  int limit4 = (blockIdx.x * SCAN_BLK) >> 2;
  const int4* c4 = (const int4*)counts;
  int s = 0;
  for (int i = tid; i < limit4; i += 256) {
    int4 v = c4[i];
    s += v.x + v.y + v.z + v.w;
  }
#pragma unroll
  for (int d = 32; d > 0; d >>= 1) s += __shfl_down(s, d, 64);
  if (lane == 0) wpart[wv] = s;
  __syncthreads();
  int blk_off = wpart[0] + wpart[1] + wpart[2] + wpart[3];

  if (blockIdx.x == 0 && tid == 0) row_ptr[N] = E;

  int base = blockIdx.x * SCAN_BLK + tid * 8;
  int v[8];
  int sl = 0;
  if (base < N) {
#pragma unroll
    for (int j = 0; j < 8; ++j) { v[j] = counts[base + j]; sl += v[j]; }
  } else {
#pragma unroll
    for (int j = 0; j < 8; ++j) v[j] = 0;
  }
  int x = sl;
#pragma unroll
  for (int d = 1; d < 64; d <<= 1) {
    int y = __shfl_up(x, d, 64);
    if (lane >= d) x += y;
  }
  if (lane == 63) wsum[wv] = x;
  __syncthreads();
  int woff = 0;
  for (int w = 0; w < wv; ++w) woff += wsum[w];
  int run = blk_off + woff + (x - sl);
  if (base < N) {
#pragma unroll
    for (int j = 0; j < 8; ++j) {
      row_ptr[base + j] = run;
      cursor[base + j] = run;
      run += v[j];
    }
  }
}

// ---------------- work1: gemm1 (f32 A, dual, bf16-interleaved out) || scatter ----------------
// Blocks [0, g1B): dual GEMM layer 1, A read directly from x (f32) with in-register
// bf16 convert (kills the separate cast pass). Blocks [g1B, g1B+cntB): scatter edges
// into packed 8B {col,val} CSR records. Independent work, one launch.
__global__ __launch_bounds__(256) void work1_kernel(const float* __restrict__ x,
                                                    const unsigned short* __restrict__ Wp,
                                                    const unsigned short* __restrict__ Gp,
                                                    unsigned* __restrict__ SG, int N, int g1B,
                                                    const int* __restrict__ rows, const int* __restrict__ cols,
                                                    const float* __restrict__ vals, int* __restrict__ cursor,
                                                    uintx2* __restrict__ colval, int E) {
  if ((int)blockIdx.x >= g1B) {
    int e = (blockIdx.x - g1B) * 256 + threadIdx.x;
    if (e >= E) return;
    int r = rows[e];
    int p = atomicAdd(&cursor[r], 1);
    uintx2 cv;
    cv[0] = (unsigned)cols[e];
    cv[1] = __float_as_uint(vals[e]);
    colval[p] = cv;
    return;
  }
  constexpr int K = 256;
  constexpr int M = 256;
  constexpr int WT = 4;
  int lane = threadIdx.x & 63;
  int wid = threadIdx.x >> 6;
  int r0 = blockIdx.x * 64;
  int quad = lane >> 4, lr = lane & 15;
  int t0 = wid * WT;

  const float* Ab[4];
#pragma unroll
  for (int g = 0; g < 4; ++g) {
    int row = r0 + g * 16 + lr;
    if (row > N - 1) row = N - 1;   // clamp loads; stores guarded below
    Ab[g] = x + (size_t)row * K + quad * 8;
  }
  const short* Wb[WT];
  const short* Gb[WT];
#pragma unroll
  for (int t = 0; t < WT; ++t) {
    size_t boff = (size_t)(t0 + t) * 16 * K + (size_t)lr * K + quad * 8;
    Wb[t] = (const short*)Wp + boff;
    Gb[t] = (const short*)Gp + boff;
  }

  floatx4 zero = {0.f, 0.f, 0.f, 0.f};
  floatx4 accS[4][WT], accG[4][WT];
#pragma unroll
  for (int g = 0; g < 4; ++g)
#pragma unroll
    for (int t = 0; t < WT; ++t) { accS[g][t] = zero; accG[g][t] = zero; }

  for (int kc = 0; kc < K / 32; ++kc) {
    short8 a[4];
#pragma unroll
    for (int g = 0; g < 4; ++g) {
      floatx4 f0 = *(const floatx4*)(Ab[g] + kc * 32);
      floatx4 f1 = *(const floatx4*)(Ab[g] + kc * 32 + 4);
      short8 av;
#pragma unroll
      for (int j = 0; j < 4; ++j) { av[j] = (short)f2bf(f0[j]); av[4 + j] = (short)f2bf(f1[j]); }
      a[g] = av;
    }
#pragma unroll
    for (int t = 0; t < WT; ++t) {
      short8 bw = *(const short8*)(Wb[t] + kc * 32);
      short8 bg = *(const short8*)(Gb[t] + kc * 32);
#pragma unroll
      for (int g = 0; g < 4; ++g) {
        accS[g][t] = __builtin_amdgcn_mfma_f32_16x16x32_bf16(a[g], bw, accS[g][t], 0, 0, 0);
        accG[g][t] = __builtin_amdgcn_mfma_f32_16x16x32_bf16(a[g], bg, accG[g][t], 0, 0, 0);
      }
    }
  }

#pragma unroll
  for (int g = 0; g < 4; ++g) {
    int orow = r0 + g * 16 + quad * 4;
#pragma unroll
    for (int t = 0; t < WT; ++t)
#pragma unroll
      for (int gg = 0; gg < 4; ++gg) {
        int row = orow + gg;
        if (row < N) {
          unsigned s = f2bf(accS[g][t][gg]);
          unsigned g2 = f2bf(accG[g][t][gg]);
          SG[(size_t)row * M + (t0 + t) * 16 + lr] = s | (g2 << 16);
        }
      }
  }
}

// ---------------- fused spmm1 + gemm2: gather/gate 16 rows -> LDS -> dual GEMM -> SG2 ----------------
// Block = 16 rows. Phase A: wave wid processes rows wid*4..wid*4+3 with the proven R4
// gather loop (4-deep 16B/lane), writes h = relu(sig(G)*S) as bf16 to LDS (stride 264).
// Phase B: 16x256 @ 256x128 dual GEMM; A-frags from LDS, B = Wp2/Gp2 (L2-hot, 128KB),
// writes SG2 interleaved bf16. Kills gemm2 launch + 50MB hb round-trip; MFMA overlaps
// other waves' gather stalls. N % 16 == 0 -> no row guards.
__global__ __launch_bounds__(256) void spmm1_gemm2_kernel(const int* __restrict__ row_ptr,
                                                          const uintx2* __restrict__ colval,
                                                          const unsigned* __restrict__ SG1,
                                                          const unsigned short* __restrict__ Wp2,
                                                          const unsigned short* __restrict__ Gp2,
                                                          unsigned* __restrict__ SG2, int N) {
  __shared__ short hlds[16 * LDS_STRIDE];
  int lane = threadIdx.x & 63;
  int wid = threadIdx.x >> 6;
  int r0 = blockIdx.x * 16;

  // ---- phase A: gather + gate 4 rows ----
  for (int rl = 0; rl < 4; ++rl) {
    int lrow = wid * 4 + rl;
    int r = r0 + lrow;
    int e0 = row_ptr[r], e1 = row_ptr[r + 1];
    float aS[4], aG[4];
#pragma unroll
    for (int i = 0; i < 4; ++i) { aS[i] = 0.f; aG[i] = 0.f; }
    int e = e0;
    for (; e + 4 <= e1; e += 4) {
      uintx2 cv0 = colval[e], cv1 = colval[e + 1], cv2 = colval[e + 2], cv3 = colval[e + 3];
      uintx4 p0 = ((const uintx4*)(SG1 + (size_t)cv0[0] * 256))[lane];
      uintx4 p1 = ((const uintx4*)(SG1 + (size_t)cv1[0] * 256))[lane];
      uintx4 p2 = ((const uintx4*)(SG1 + (size_t)cv2[0] * 256))[lane];
      uintx4 p3 = ((const uintx4*)(SG1 + (size_t)cv3[0] * 256))[lane];
      float v0 = __uint_as_float(cv0[1]), v1 = __uint_as_float(cv1[1]);
      float v2 = __uint_as_float(cv2[1]), v3 = __uint_as_float(cv3[1]);
#pragma unroll
      for (int q = 0; q < 4; ++q) { aS[q] += __uint_as_float(p0[q] << 16) * v0; aG[q] += __uint_as_float(p0[q]) * v0; }
#pragma unroll
      for (int q = 0; q < 4; ++q) { aS[q] += __uint_as_float(p1[q] << 16) * v1; aG[q] += __uint_as_float(p1[q]) * v1; }
#pragma unroll
      for (int q = 0; q < 4; ++q) { aS[q] += __uint_as_float(p2[q] << 16) * v2; aG[q] += __uint_as_float(p2[q]) * v2; }
#pragma unroll
      for (int q = 0; q < 4; ++q) { aS[q] += __uint_as_float(p3[q] << 16) * v3; aG[q] += __uint_as_float(p3[q]) * v3; }
    }
    for (; e < e1; ++e) {
      uintx2 cv = colval[e];
      uintx4 p = ((const uintx4*)(SG1 + (size_t)cv[0] * 256))[lane];
      float v = __uint_as_float(cv[1]);
#pragma unroll
      for (int q = 0; q < 4; ++q) { aS[q] += __uint_as_float(p[q] << 16) * v; aG[q] += __uint_as_float(p[q]) * v; }
    }
    ushortx4 o;
#pragma unroll
    for (int i = 0; i < 4; ++i) {
      float h = sigmoidf(aG[i]) * aS[i];
      o[i] = f2bf(h > 0.f ? h : 0.f);
    }
    *(ushortx4*)(&hlds[lrow * LDS_STRIDE + lane * 4]) = o;
  }
  __syncthreads();

  // ---- phase B: 16x256 @ 256x128 dual GEMM from LDS ----
  constexpr int K = 256;
  int quad = lane >> 4, lr = lane & 15;
  int t0 = wid * 2;
  const short* Wb0 = (const short*)Wp2 + (size_t)(t0 + 0) * 16 * K + (size_t)lr * K + quad * 8;
  const short* Wb1 = (const short*)Wp2 + (size_t)(t0 + 1) * 16 * K + (size_t)lr * K + quad * 8;
  const short* Gb0 = (const short*)Gp2 + (size_t)(t0 + 0) * 16 * K + (size_t)lr * K + quad * 8;
  const short* Gb1 = (const short*)Gp2 + (size_t)(t0 + 1) * 16 * K + (size_t)lr * K + quad * 8;
  const short* Abase = &hlds[lr * LDS_STRIDE + quad * 8];

  floatx4 zero = {0.f, 0.f, 0.f, 0.f};
  floatx4 accS[2] = {zero, zero}, accG[2] = {zero, zero};
#pragma unroll
  for (int kc = 0; kc < 8; ++kc) {
    short8 a = *(const short8*)(Abase + kc * 32);
    short8 bw0 = *(const short8*)(Wb0 + kc * 32);
    short8 bw1 = *(const short8*)(Wb1 + kc * 32);
    short8 bg0 = *(const short8*)(Gb0 + kc * 32);
    short8 bg1 = *(const short8*)(Gb1 + kc * 32);
    accS[0] = __builtin_amdgcn_mfma_f32_16x16x32_bf16(a, bw0, accS[0], 0, 0, 0);
    accS[1] = __builtin_amdgcn_mfma_f32_16x16x32_bf16(a, bw1, accS[1], 0, 0, 0);
    accG[0] = __builtin_amdgcn_mfma_f32_16x16x32_bf16(a, bg0, accG[0], 0, 0, 0);
    accG[1] = __builtin_amdgcn_mfma_f32_16x16x32_bf16(a, bg1, accG[1], 0, 0, 0);
  }
#pragma unroll
  for (int t = 0; t < 2; ++t)
#pragma unroll
    for (int gg = 0; gg < 4; ++gg) {
      int row = r0 + quad * 4 + gg;
      unsigned s = f2bf(accS[t][gg]);
      unsigned g2 = f2bf(accG[t][gg]);
      SG2[(size_t)row * 128 + (t0 + t) * 16 + lr] = s | (g2 << 16);
    }
}

// ---------------- spmm2: final gather + gate, f32 out ----------------
__global__ __launch_bounds__(256) void spmm2_kernel(const int* __restrict__ row_ptr,
                                                    const uintx2* __restrict__ colval,
                                                    const unsigned* __restrict__ SG,
                                                    float* __restrict__ out, int N) {
  int lane = threadIdx.x & 63;
  int wid = threadIdx.x >> 6;
  int r = blockIdx.x * 4 + wid;
  if (r >= N) return;
  int e0 = row_ptr[r], e1 = row_ptr[r + 1];

  float aS[2] = {0.f, 0.f}, aG[2] = {0.f, 0.f};
  int e = e0;
  for (; e + 4 <= e1; e += 4) {
    uintx2 cv0 = colval[e], cv1 = colval[e + 1], cv2 = colval[e + 2], cv3 = colval[e + 3];
    uintx2 p0 = ((const uintx2*)(SG + (size_t)cv0[0] * 128))[lane];
    uintx2 p1 = ((const uintx2*)(SG + (size_t)cv1[0] * 128))[lane];
    uintx2 p2 = ((const uintx2*)(SG + (size_t)cv2[0] * 128))[lane];
    uintx2 p3 = ((const uintx2*)(SG + (size_t)cv3[0] * 128))[lane];
    float v0 = __uint_as_float(cv0[1]), v1 = __uint_as_float(cv1[1]);
    float v2 = __uint_as_float(cv2[1]), v3 = __uint_as_float(cv3[1]);
#pragma unroll
    for (int q = 0; q < 2; ++q) { aS[q] += __uint_as_float(p0[q] << 16) * v0; aG[q] += __uint_as_float(p0[q]) * v0; }
#pragma unroll
    for (int q = 0; q < 2; ++q) { aS[q] += __uint_as_float(p1[q] << 16) * v1; aG[q] += __uint_as_float(p1[q]) * v1; }
#pragma unroll
    for (int q = 0; q < 2; ++q) { aS[q] += __uint_as_float(p2[q] << 16) * v2; aG[q] += __uint_as_float(p2[q]) * v2; }
#pragma unroll
    for (int q = 0; q < 2; ++q) { aS[q] += __uint_as_float(p3[q] << 16) * v3; aG[q] += __uint_as_float(p3[q]) * v3; }
  }
  for (; e < e1; ++e) {
    uintx2 cv = colval[e];
    uintx2 p = ((const uintx2*)(SG + (size_t)cv[0] * 128))[lane];
    float v = __uint_as_float(cv[1]);
#pragma unroll
    for (int q = 0; q < 2; ++q) { aS[q] += __uint_as_float(p[q] << 16) * v; aG[q] += __uint_as_float(p[q]) * v; }
  }
  floatx2 o;
#pragma unroll
  for (int i = 0; i < 2; ++i) o[i] = sigmoidf(aG[i]) * aS[i];
  ((floatx2*)(out + (size_t)r * 128))[lane] = o;
}

// ---------------- launch ----------------

extern "C" void kernel_launch(void* const* d_in, const int* in_sizes, int n_in,
                              void* d_out, int out_size, void* d_ws, size_t ws_size,
                              hipStream_t stream) {
  const float* x    = (const float*)d_in[0];
  const int*   rows = (const int*)d_in[1];
  const int*   cols = (const int*)d_in[2];
  const float* vals = (const float*)d_in[3];
  const float* W1   = (const float*)d_in[4];
  const float* G1   = (const float*)d_in[5];
  const float* W2   = (const float*)d_in[6];
  const float* G2   = (const float*)d_in[7];

  const int N = N_NODES, E = N_EDGES;
  char* ws = (char*)d_ws;
  size_t off = 0;
  auto alloc = [&](size_t bytes) -> char* {
    off = (off + 255) & ~(size_t)255;
    char* p = ws + off;
    off += bytes;
    return p;
  };
  int*   counts  = (int*)alloc((size_t)N * 4);
  int*   row_ptr = (int*)alloc((size_t)(N + 1) * 4);
  int*   cursor  = (int*)alloc((size_t)N * 4);
  uintx2* colval = (uintx2*)alloc((size_t)E * 8);
  unsigned short* Wp1 = (unsigned short*)alloc(256 * 256 * 2);
  unsigned short* Gp1 = (unsigned short*)alloc(256 * 256 * 2);
  unsigned short* Wp2 = (unsigned short*)alloc(256 * 128 * 2);
  unsigned short* Gp2 = (unsigned short*)alloc(256 * 128 * 2);
  unsigned* SG1 = (unsigned*)alloc((size_t)N * 256 * 4);   // [N][256] uints = {S,G} bf16 pairs
  unsigned* SG2 = (unsigned*)alloc((size_t)N * 128 * 4);   // [N][128] uints

  (void)hipMemsetAsync(counts, 0, (size_t)N * 4, stream);

  int cntB = (E + 255) / 256;           // 3125
  prep_kernel<<<cntB + 768, 256, 0, stream>>>(rows, counts, E, cntB,
                                              W1, G1, W2, G2, Wp1, Gp1, Wp2, Gp2);

  int scanB = (N + SCAN_BLK - 1) / SCAN_BLK;   // 25
  scan_kernel<<<scanB, 256, 0, stream>>>(counts, row_ptr, cursor, N, E);

  // gemm1 (f32 A) || scatter
  int g1B = (N + 63) / 64;              // 782
  work1_kernel<<<g1B + cntB, 256, 0, stream>>>(x, Wp1, Gp1, SG1, N, g1B,
                                               rows, cols, vals, cursor, colval, E);

  // fused spmm1 + gemm2  (N % 16 == 0)
  spmm1_gemm2_kernel<<<N / 16, 256, 0, stream>>>(row_ptr, colval, SG1, Wp2, Gp2, SG2, N);

  // final spmm
  spmm2_kernel<<<(N + 3) / 4, 256, 0, stream>>>(row_ptr, colval, SG2, (float*)d_out, N);
}